// Round 1
// baseline (12.059 us; speedup 1.0000x reference)
//
#include <hip/hip_runtime.h>

// PointChargeField: out[b,n,:] = sum_m q[b,m] * (p[b,n,:]-c[b,m,:]) / |p-c|^3
// B=8, N=2048, M=1024, all fp32.
// Compute-bound FP32 N-body; one block = (b, 32-n tile); thread = 4 n x 32 m.

#define B_ 8
#define N_ 2048
#define M_ 1024

__global__ __launch_bounds__(256) void pcf_kernel(
    const float* __restrict__ positions,        // [B,N,3]
    const float* __restrict__ charges,          // [B,M]
    const float* __restrict__ charge_positions, // [B,M,3]
    float* __restrict__ out)                    // [B,N,3]
{
    __shared__ float4 pack[M_];       // (cx,cy,cz,q) per charge
    __shared__ float  red[32][100];   // 32 chunks x (32 n * 3 c), padded

    const int tid = threadIdx.x;
    const int blk = blockIdx.x;
    const int b      = blk >> 6;          // 64 n-tiles per batch
    const int n_base = (blk & 63) << 5;   // tile covers 32 n-points

    const float* cp = charge_positions + (size_t)b * M_ * 3;
    const float* qp = charges          + (size_t)b * M_;

    // Stage packed charge data into LDS (one-time; inputs are L2-resident).
    #pragma unroll
    for (int j = 0; j < 4; ++j) {
        int m = tid + 256 * j;
        pack[m] = make_float4(cp[3*m], cp[3*m+1], cp[3*m+2], qp[m]);
    }
    __syncthreads();

    const int n4    = tid & 7;    // which of 8 n-lanes
    const int chunk = tid >> 3;   // 0..31: which 32-m chunk

    // Positions for this thread's 4 n-points.
    float px[4], py[4], pz[4];
    #pragma unroll
    for (int k = 0; k < 4; ++k) {
        int n = n_base + n4 + 8 * k;
        const float* p = positions + ((size_t)b * N_ + n) * 3;
        px[k] = p[0]; py[k] = p[1]; pz[k] = p[2];
    }

    float ax[4] = {0,0,0,0}, ay[4] = {0,0,0,0}, az[4] = {0,0,0,0};

    // m = chunk + 32*i: per-wave b128 addresses hit banks {4c mod 32} -> conflict-free.
    #pragma unroll 4
    for (int i = 0; i < 32; ++i) {
        int m = chunk + (i << 5);
        float4 c = pack[m];
        #pragma unroll
        for (int k = 0; k < 4; ++k) {
            float dx = px[k] - c.x;
            float dy = py[k] - c.y;
            float dz = pz[k] - c.z;
            float r2 = fmaf(dx, dx, fmaf(dy, dy, dz * dz));
            float ir  = __builtin_amdgcn_rsqf(r2);   // v_rsq_f32, ~1 ulp
            float ir2 = ir * ir;
            float s   = c.w * ir * ir2;              // q / r^3
            ax[k] = fmaf(s, dx, ax[k]);
            ay[k] = fmaf(s, dy, ay[k]);
            az[k] = fmaf(s, dz, az[k]);
        }
    }

    // Cross-chunk reduction in LDS.
    #pragma unroll
    for (int k = 0; k < 4; ++k) {
        int nl = n4 + 8 * k;
        red[chunk][nl * 3 + 0] = ax[k];
        red[chunk][nl * 3 + 1] = ay[k];
        red[chunk][nl * 3 + 2] = az[k];
    }
    __syncthreads();

    if (tid < 96) {
        float s = 0.f;
        #pragma unroll
        for (int ch = 0; ch < 32; ++ch) s += red[ch][tid];
        out[((size_t)b * N_ + n_base) * 3 + tid] = s;
    }
}

extern "C" void kernel_launch(void* const* d_in, const int* in_sizes, int n_in,
                              void* d_out, int out_size, void* d_ws, size_t ws_size,
                              hipStream_t stream) {
    const float* positions        = (const float*)d_in[0];  // [8,2048,3]
    const float* charges          = (const float*)d_in[1];  // [8,1024]
    const float* charge_positions = (const float*)d_in[2];  // [8,1024,3]
    float* out = (float*)d_out;                             // [8,2048,3]

    dim3 grid(B_ * (N_ / 32));   // 512 blocks
    dim3 block(256);
    pcf_kernel<<<grid, block, 0, stream>>>(positions, charges, charge_positions, out);
}